// Round 2
// baseline (185.359 us; speedup 1.0000x reference)
//
#include <hip/hip_runtime.h>

#define NCLS 20
#define KNBR 16
#define TPP 4              // threads per point; each handles KNBR/TPP=4 neighbors
#define IGNORE_INDEX (-1)

// Load an 80B logits row and compute its softmax into v[20].
__device__ __forceinline__ void softmax_row(const float* __restrict__ row, float* v) {
    const float4* r4 = (const float4*)row;
#pragma unroll
    for (int q = 0; q < 5; ++q) {
        float4 t = r4[q];
        v[4 * q + 0] = t.x; v[4 * q + 1] = t.y;
        v[4 * q + 2] = t.z; v[4 * q + 3] = t.w;
    }
    float m = v[0];
#pragma unroll
    for (int c = 1; c < NCLS; ++c) m = fmaxf(m, v[c]);
    float s = 0.f;
#pragma unroll
    for (int c = 0; c < NCLS; ++c) { v[c] = __expf(v[c] - m); s += v[c]; }
    float inv = 1.0f / s;
#pragma unroll
    for (int c = 0; c < NCLS; ++c) v[c] *= inv;
}

// -------- fused kernel: softmax-on-the-fly masked pairwise distance ---------
__global__ __launch_bounds__(256) void fused_loss_kernel(
    const float* __restrict__ logits, const int* __restrict__ labels,
    const int* __restrict__ ref_idx,
    double* __restrict__ sum_acc, unsigned int* __restrict__ cnt_acc, int n) {
    int tid = blockIdx.x * blockDim.x + threadIdx.x;
    int p = tid >> 2;          // point index
    int t = tid & (TPP - 1);   // which quarter of the neighbor list

    float fsum = 0.f;
    unsigned int cnt = 0;

    if (p < n) {
        int li = labels[p];
        // one coalesced int4 load: neighbors [t*4, t*4+3] of point p
        int4 r4 = ((const int4*)ref_idx)[(size_t)p * TPP + t];
        int rr[4] = {r4.x, r4.y, r4.z, r4.w};
        // 4 independent label gathers, unconditional (labels is 1MB -> L2-hot)
        int nl[4];
#pragma unroll
        for (int j = 0; j < 4; ++j) nl[j] = labels[max(rr[j], 0)];
        bool m[4];
        int any = 0;
#pragma unroll
        for (int j = 0; j < 4; ++j) {
            m[j] = (rr[j] >= 0) && (li != IGNORE_INDEX) &&
                   (nl[j] != IGNORE_INDEX) && (nl[j] == li);
            any |= (int)m[j];
        }
        if (any) {
            float pc[NCLS];
            softmax_row(logits + (size_t)p * NCLS, pc);
#pragma unroll
            for (int j = 0; j < 4; ++j) {
                if (!m[j]) continue;
                float qc[NCLS];
                softmax_row(logits + (size_t)rr[j] * NCLS, qc);
                float d = 0.f;
#pragma unroll
                for (int c = 0; c < NCLS; ++c) {
                    float dx = pc[c] - qc[c];
                    d = fmaf(dx, dx, d);
                }
                fsum += d;
                cnt += 1u;
            }
        }
    }

    // wave64 shuffle reduce (float sum + uint count)
#pragma unroll
    for (int off = 32; off > 0; off >>= 1) {
        fsum += __shfl_down(fsum, off, 64);
        cnt  += __shfl_down(cnt,  off, 64);
    }
    __shared__ float s_sum[4];
    __shared__ unsigned int s_cnt[4];
    int wave = threadIdx.x >> 6;
    int lane = threadIdx.x & 63;
    if (lane == 0) { s_sum[wave] = fsum; s_cnt[wave] = cnt; }
    __syncthreads();
    if (threadIdx.x == 0) {
        double bs = (double)s_sum[0] + (double)s_sum[1] +
                    (double)s_sum[2] + (double)s_sum[3];
        unsigned int bc = s_cnt[0] + s_cnt[1] + s_cnt[2] + s_cnt[3];
        atomicAdd(sum_acc, bs);
        atomicAdd(cnt_acc, bc);
    }
}

// -------- finalize ----------------------------------------------------------
__global__ void finalize_kernel(const double* __restrict__ sum_acc,
                                const unsigned int* __restrict__ cnt_acc,
                                float* __restrict__ out) {
    double s = *sum_acc;
    double c = (double)max(*cnt_acc, 1u);
    out[0] = (float)(s / c);   // LOSS_WEIGHT = 1.0
}

extern "C" void kernel_launch(void* const* d_in, const int* in_sizes, int n_in,
                              void* d_out, int out_size, void* d_ws, size_t ws_size,
                              hipStream_t stream) {
    const float* seg_logits = (const float*)d_in[0];
    // d_in[1] = coord — unused (KNN indices are given)
    const int* labels  = (const int*)d_in[2];
    const int* ref_idx = (const int*)d_in[3];
    float* out = (float*)d_out;
    const int n = in_sizes[2];                 // 262144

    double* sum_acc = (double*)d_ws;
    unsigned int* cnt_acc = (unsigned int*)((char*)d_ws + sizeof(double));

    // zero the 16-byte accumulator region (graph-capturable)
    hipMemsetAsync(d_ws, 0, 16, stream);

    int threads = n * TPP;                     // 1,048,576
    int blocks = (threads + 255) / 256;        // 4096
    fused_loss_kernel<<<blocks, 256, 0, stream>>>(seg_logits, labels, ref_idx,
                                                  sum_acc, cnt_acc, n);
    finalize_kernel<<<1, 1, 0, stream>>>(sum_acc, cnt_acc, out);
}

// Round 4
// 138.008 us; speedup vs baseline: 1.3431x; 1.3431x over previous
//
#include <hip/hip_runtime.h>

#define NCLS 20
#define BPTS 256            // points per block == block size
#define IGNORE_INDEX (-1)

__device__ __forceinline__ void load_row(const float* __restrict__ row, float* v) {
    const float4* r4 = (const float4*)row;   // rows are 80B = 5*16B, always 16B-aligned
#pragma unroll
    for (int q = 0; q < 5; ++q) {
        float4 t = r4[q];
        v[4 * q + 0] = t.x; v[4 * q + 1] = t.y;
        v[4 * q + 2] = t.z; v[4 * q + 3] = t.w;
    }
}

__device__ __forceinline__ void softmax_inplace(float* v) {
    float m = v[0];
#pragma unroll
    for (int c = 1; c < NCLS; ++c) m = fmaxf(m, v[c]);
    float s = 0.f;
#pragma unroll
    for (int c = 0; c < NCLS; ++c) { v[c] = __expf(v[c] - m); s += v[c]; }
    float inv = 1.0f / s;
#pragma unroll
    for (int c = 0; c < NCLS; ++c) v[c] *= inv;
}

// Single fused kernel: compact surviving pairs into LDS, then process them
// with full-lane gathers + inline softmax. Last block finalizes the scalar.
__global__ __launch_bounds__(256) void lac_kernel(
    const float* __restrict__ logits, const int* __restrict__ labels,
    const int* __restrict__ ref_idx,
    double* __restrict__ sum_acc, unsigned int* __restrict__ cnt_acc,
    unsigned int* __restrict__ ticket, float* __restrict__ out, int n) {

    // 16 KB: packed (local_center << 24) | neighbor — UNSIGNED: tid>=128 would
    // set the sign bit and an arithmetic >>24 would sign-extend (R3 crash).
    __shared__ unsigned int s_pairs[BPTS * 16];
    __shared__ int s_npairs;
    __shared__ float s_wsum[4];
    __shared__ unsigned int s_wcnt[4];

    const int tid = threadIdx.x;
    if (tid == 0) s_npairs = 0;
    __syncthreads();

    // ---- phase 1: build survival mask, compact pairs into LDS --------------
    const int p = blockIdx.x * BPTS + tid;
    if (p < n) {
        const int li = labels[p];
        const int4* r4 = (const int4*)(ref_idx + (size_t)p * 16);
        int4 ra = r4[0], rb = r4[1], rc = r4[2], rd = r4[3];
        int rr[16] = {ra.x, ra.y, ra.z, ra.w, rb.x, rb.y, rb.z, rb.w,
                      rc.x, rc.y, rc.z, rc.w, rd.x, rd.y, rd.z, rd.w};
        int nl[16];
#pragma unroll
        for (int j = 0; j < 16; ++j) nl[j] = labels[max(rr[j], 0)];  // independent gathers
        if (li != IGNORE_INDEX) {
#pragma unroll
            for (int j = 0; j < 16; ++j) {
                // nl[j]==li implies nl[j] != IGNORE_INDEX since li >= 0
                if (rr[j] >= 0 && nl[j] == li) {
                    int slot = atomicAdd(&s_npairs, 1);
                    s_pairs[slot] = ((unsigned int)tid << 24) | (unsigned int)rr[j];
                }
            }
        }
    }
    __syncthreads();
    const int np = s_npairs;

    // ---- phase 2: process compacted pairs, full-lane ------------------------
    float fsum = 0.f;
    unsigned int pcnt = 0;
    for (int t = tid; t < np; t += BPTS) {
        unsigned int pk = s_pairs[t];
        int lp = (int)(pk >> 24);          // logical shift: lp in [0,255]
        int r  = (int)(pk & 0xFFFFFFu);
        float a[NCLS], b[NCLS];
        load_row(logits + (size_t)(blockIdx.x * BPTS + lp) * NCLS, a);
        load_row(logits + (size_t)r * NCLS, b);
        softmax_inplace(a);
        softmax_inplace(b);
        float d = 0.f;
#pragma unroll
        for (int c = 0; c < NCLS; ++c) {
            float dx = a[c] - b[c];
            d = fmaf(dx, dx, d);
        }
        fsum += d;
        pcnt += 1u;
    }

    // ---- block reduction ----------------------------------------------------
#pragma unroll
    for (int off = 32; off > 0; off >>= 1) {
        fsum += __shfl_down(fsum, off, 64);
        pcnt += __shfl_down(pcnt, off, 64);
    }
    const int wave = tid >> 6;
    const int lane = tid & 63;
    if (lane == 0) { s_wsum[wave] = fsum; s_wcnt[wave] = pcnt; }
    __syncthreads();

    if (tid == 0) {
        double bs = (double)s_wsum[0] + (double)s_wsum[1] +
                    (double)s_wsum[2] + (double)s_wsum[3];
        unsigned int bc = s_wcnt[0] + s_wcnt[1] + s_wcnt[2] + s_wcnt[3];
        atomicAdd(sum_acc, bs);
        atomicAdd(cnt_acc, bc);
        __threadfence();                      // publish before taking ticket
        unsigned int tk = atomicAdd(ticket, 1u);
        if (tk == gridDim.x - 1) {            // last block: finalize
            double s = atomicAdd(sum_acc, 0.0);          // coherent read of total
            unsigned int c = atomicAdd(cnt_acc, 0u);
            out[0] = (float)(s / (double)max(c, 1u));    // LOSS_WEIGHT = 1.0
        }
    }
}

extern "C" void kernel_launch(void* const* d_in, const int* in_sizes, int n_in,
                              void* d_out, int out_size, void* d_ws, size_t ws_size,
                              hipStream_t stream) {
    const float* seg_logits = (const float*)d_in[0];
    // d_in[1] = coord — unused (KNN indices are given)
    const int* labels  = (const int*)d_in[2];
    const int* ref_idx = (const int*)d_in[3];
    float* out = (float*)d_out;
    const int n = in_sizes[2];                 // 262144

    double* sum_acc       = (double*)d_ws;
    unsigned int* cnt_acc = (unsigned int*)((char*)d_ws + 8);
    unsigned int* ticket  = (unsigned int*)((char*)d_ws + 12);

    hipMemsetAsync(d_ws, 0, 16, stream);       // zero sum/cnt/ticket

    int blocks = (n + BPTS - 1) / BPTS;        // 1024
    lac_kernel<<<blocks, BPTS, 0, stream>>>(seg_logits, labels, ref_idx,
                                            sum_acc, cnt_acc, ticket, out, n);
}